// Round 1
// baseline (9610.465 us; speedup 1.0000x reference)
//
#include <hip/hip_runtime.h>
#include <stdint.h>

// ---------------- problem constants ----------------
#define B_SZ   256
#define SEQ_LEN 128
#define DIN    1024
#define DHID   2048
#define NCLS   1024

typedef unsigned short ushort_t;
typedef short bf16x8 __attribute__((ext_vector_type(8)));
typedef float f32x16 __attribute__((ext_vector_type(16)));

__device__ __forceinline__ ushort_t f32_to_bf16(float f) {
  uint32_t u = __builtin_bit_cast(uint32_t, f);
  u = (u + 0x7FFFu + ((u >> 16) & 1u)) >> 16;
  return (ushort_t)u;
}
__device__ __forceinline__ float bf16_to_f32(ushort_t h) {
  uint32_t u = ((uint32_t)h) << 16;
  return __builtin_bit_cast(float, u);
}

// async global->LDS, 16B per lane. LDS dest is wave-uniform base + lane*16.
__device__ __forceinline__ void llds16(const ushort_t* g, ushort_t* l) {
  __builtin_amdgcn_global_load_lds(
      (const __attribute__((address_space(1))) void*)g,
      (__attribute__((address_space(3))) void*)l, 16, 0, 0);
}

#define VMCNT_IMM_4 (0x3FF0 | 4)
#define VMCNT_IMM_0 (0x3FF0 | 0)

// ---------------- conversion kernels ----------------
__global__ void k_split(const float* __restrict__ s, ushort_t* __restrict__ hi,
                        ushort_t* __restrict__ lo, int n4) {
  int i = blockIdx.x * 256 + threadIdx.x;
  if (i >= n4) return;
  float4 v = ((const float4*)s)[i];
  ushort_t h0 = f32_to_bf16(v.x), h1 = f32_to_bf16(v.y);
  ushort_t h2 = f32_to_bf16(v.z), h3 = f32_to_bf16(v.w);
  ushort4 hv; hv.x = h0; hv.y = h1; hv.z = h2; hv.w = h3;
  ushort4 lv;
  lv.x = f32_to_bf16(v.x - bf16_to_f32(h0));
  lv.y = f32_to_bf16(v.y - bf16_to_f32(h1));
  lv.z = f32_to_bf16(v.z - bf16_to_f32(h2));
  lv.w = f32_to_bf16(v.w - bf16_to_f32(h3));
  ((ushort4*)hi)[i] = hv;
  ((ushort4*)lo)[i] = lv;
}

__global__ void k_cvt(const float* __restrict__ s, ushort_t* __restrict__ d, int n4) {
  int i = blockIdx.x * 256 + threadIdx.x;
  if (i >= n4) return;
  float4 v = ((const float4*)s)[i];
  ushort4 hv;
  hv.x = f32_to_bf16(v.x); hv.y = f32_to_bf16(v.y);
  hv.z = f32_to_bf16(v.z); hv.w = f32_to_bf16(v.w);
  ((ushort4*)d)[i] = hv;
}

// ---------------- segmented-K GEMM ----------------
// C[M,N] = sum_seg A_seg[M,Kseg] * B_seg[N,Kseg]^T  (+ bias), M,N mult of 64,
// Kseg mult of 64. Block tile 64x64, 4 waves split K (wave w owns k%64 in
// [16w,16w+16)), mfma_f32_32x32x16_bf16, LDS-reduced partials.
struct Seg {
  const ushort_t* A;
  const ushort_t* B;
  int a_stride;
  int b_stride;
  int k_len;
};
struct Args {
  Seg seg[4];
  int n_seg;
  int n_iters;          // total K / 64
  const float* bias;    // [N]
  ushort_t* out_hi;     // bf16 hi out (or null)
  ushort_t* out_lo;     // bf16 lo out
  float* out_f32;       // fp32 out (or null)
  int ldo;              // out leading dim
};

__global__ __launch_bounds__(256, 1) void k_gemm(Args args) {
  __shared__ __align__(16) ushort_t sA[2][4096];  // 2 x 8KB (64x64 bf16)
  __shared__ __align__(16) ushort_t sB[2][4096];
  __shared__ __align__(16) float    sR[8192];     // 32KB reduce scratch

  const int tid  = threadIdx.x;
  const int lane = tid & 63;
  const int wv   = tid >> 6;
  const int bm0  = blockIdx.y * 64;
  const int bn0  = blockIdx.x * 64;

  f32x16 acc[2][2];
#pragma unroll
  for (int a = 0; a < 2; ++a)
#pragma unroll
    for (int b = 0; b < 2; ++b)
#pragma unroll
      for (int r = 0; r < 16; ++r) acc[a][b][r] = 0.0f;

  // staging mapping: physical slot tp (=tid + 256*r) covers LDS bytes tp*16;
  // it fetches global chunk glc = (tp&7) ^ (prow&7)  (xor swizzle).
  const int prow0 = tid >> 3;
  const int glc0  = (tid & 7) ^ (prow0 & 7);
  const int prow1 = (tid + 256) >> 3;
  const int glc1  = (tid & 7) ^ (prow1 & 7);

  auto stage = [&](int buf, const Seg& sg, int k0) {
    const ushort_t* ga0 = sg.A + (size_t)(bm0 + prow0) * sg.a_stride + (k0 + glc0 * 8);
    const ushort_t* ga1 = sg.A + (size_t)(bm0 + prow1) * sg.a_stride + (k0 + glc1 * 8);
    const ushort_t* gb0 = sg.B + (size_t)(bn0 + prow0) * sg.b_stride + (k0 + glc0 * 8);
    const ushort_t* gb1 = sg.B + (size_t)(bn0 + prow1) * sg.b_stride + (k0 + glc1 * 8);
    ushort_t* la = &sA[buf][wv * 512];
    ushort_t* lb = &sB[buf][wv * 512];
    llds16(ga0, la);
    llds16(ga1, la + 2048);
    llds16(gb0, lb);
    llds16(gb1, lb + 2048);
  };

  int sc = 0, kc = 0;
  stage(0, args.seg[0], 0);
  kc = 64;
  if (kc >= args.seg[0].k_len) { kc = 0; sc = 1; }

  const int nit  = args.n_iters;
  const int half = lane >> 5;
  const int l31  = lane & 31;
  const int lch  = wv * 2 + half;  // this wave's logical 16B-chunk within row

  for (int i = 0; i < nit; ++i) {
    const int buf = i & 1;
    if (i + 1 < nit) {
      stage(buf ^ 1, args.seg[sc], kc);
      kc += 64;
      if (kc >= args.seg[sc].k_len) { kc = 0; ++sc; }
      __builtin_amdgcn_s_waitcnt(VMCNT_IMM_4);  // oldest 4 (this tile) done
    } else {
      __builtin_amdgcn_s_waitcnt(VMCNT_IMM_0);
    }
    __builtin_amdgcn_s_barrier();

    bf16x8 af[2], bfm[2];
#pragma unroll
    for (int mi = 0; mi < 2; ++mi) {
      int row = mi * 32 + l31;
      int pch = lch ^ (row & 7);
      af[mi] = *(const bf16x8*)&sA[buf][row * 64 + pch * 8];
    }
#pragma unroll
    for (int ni = 0; ni < 2; ++ni) {
      int row = ni * 32 + l31;
      int pch = lch ^ (row & 7);
      bfm[ni] = *(const bf16x8*)&sB[buf][row * 64 + pch * 8];
    }
#pragma unroll
    for (int mi = 0; mi < 2; ++mi)
#pragma unroll
      for (int ni = 0; ni < 2; ++ni)
        acc[mi][ni] = __builtin_amdgcn_mfma_f32_32x32x16_bf16(
            af[mi], bfm[ni], acc[mi][ni], 0, 0, 0);

    __builtin_amdgcn_s_barrier();  // consume-done before next overwrite
  }

  // ---- reduce 4 wave-partials through LDS ----
  float* red;
  if (wv == 0)      red = (float*)&sA[0][0];
  else if (wv == 1) red = (float*)&sB[0][0];
  else if (wv == 2) red = sR;
  else              red = sR + 4096;

#pragma unroll
  for (int mi = 0; mi < 2; ++mi)
#pragma unroll
    for (int ni = 0; ni < 2; ++ni)
#pragma unroll
      for (int r = 0; r < 16; ++r) {
        int row = mi * 32 + (r & 3) + 8 * (r >> 2) + 4 * half;
        int col = ni * 32 + l31;
        red[row * 64 + col] = acc[mi][ni][r];
      }
  __syncthreads();

  const float* r0 = (const float*)&sA[0][0];
  const float* r1 = (const float*)&sB[0][0];
  const float* r2 = sR;
  const float* r3 = sR + 4096;
#pragma unroll
  for (int j = 0; j < 16; ++j) {
    int e = j * 256 + tid;
    int row = e >> 6, col = e & 63;
    float v = r0[e] + r1[e] + r2[e] + r3[e] + args.bias[bn0 + col];
    size_t o = (size_t)(bm0 + row) * args.ldo + (bn0 + col);
    if (args.out_f32) {
      args.out_f32[o] = v;
    } else {
      ushort_t h = f32_to_bf16(v);
      args.out_hi[o] = h;
      args.out_lo[o] = f32_to_bf16(v - bf16_to_f32(h));
    }
  }
}

// ---------------- launch ----------------
extern "C" void kernel_launch(void* const* d_in, const int* in_sizes, int n_in,
                              void* d_out, int out_size, void* d_ws, size_t ws_size,
                              hipStream_t stream) {
  const float* x   = (const float*)d_in[0];
  const float* Whx = (const float*)d_in[1];
  const float* Whh = (const float*)d_in[2];
  const float* Wph = (const float*)d_in[3];
  const float* bh  = (const float*)d_in[4];
  const float* bp  = (const float*)d_in[5];

  char* p = (char*)d_ws;
  ushort_t* whh_hi = (ushort_t*)p; p += (size_t)DHID * DHID * 2;
  ushort_t* whh_lo = (ushort_t*)p; p += (size_t)DHID * DHID * 2;
  ushort_t* whx_b  = (ushort_t*)p; p += (size_t)DHID * DIN * 2;
  ushort_t* wph_b  = (ushort_t*)p; p += (size_t)NCLS * DHID * 2;
  ushort_t* x_b    = (ushort_t*)p; p += (size_t)B_SZ * SEQ_LEN * DIN * 2;
  ushort_t* h_hi[2]; ushort_t* h_lo[2];
  h_hi[0] = (ushort_t*)p; p += (size_t)B_SZ * DHID * 2;
  h_lo[0] = (ushort_t*)p; p += (size_t)B_SZ * DHID * 2;
  h_hi[1] = (ushort_t*)p; p += (size_t)B_SZ * DHID * 2;
  h_lo[1] = (ushort_t*)p; p += (size_t)B_SZ * DHID * 2;

  // weight / input conversions (inputs re-poisoned every call, so redo each launch)
  {
    int n4 = DHID * DHID / 4;
    k_split<<<(n4 + 255) / 256, 256, 0, stream>>>(Whh, whh_hi, whh_lo, n4);
  }
  {
    int n4 = DHID * DIN / 4;
    k_cvt<<<(n4 + 255) / 256, 256, 0, stream>>>(Whx, whx_b, n4);
  }
  {
    int n4 = NCLS * DHID / 4;
    k_cvt<<<(n4 + 255) / 256, 256, 0, stream>>>(Wph, wph_b, n4);
  }
  {
    int n4 = B_SZ * SEQ_LEN * DIN / 4;
    k_cvt<<<(n4 + 255) / 256, 256, 0, stream>>>(x, x_b, n4);
  }

  dim3 blk(256);
  // t = 0: h = x_0 @ Whx^T + b_h
  {
    Args a = {};
    a.seg[0] = { x_b, whx_b, SEQ_LEN * DIN, DIN, DIN };
    a.n_seg = 1; a.n_iters = DIN / 64;
    a.bias = bh; a.out_hi = h_hi[0]; a.out_lo = h_lo[0]; a.out_f32 = nullptr;
    a.ldo = DHID;
    k_gemm<<<dim3(DHID / 64, B_SZ / 64), blk, 0, stream>>>(a);
  }
  // t = 1..127: h = h_prev @ Whh^T (3-product hi/lo) + x_t @ Whx^T + b_h
  for (int t = 1; t < SEQ_LEN; ++t) {
    int w = t & 1, r = w ^ 1;
    Args a = {};
    a.seg[0] = { h_hi[r], whh_hi, DHID, DHID, DHID };
    a.seg[1] = { h_hi[r], whh_lo, DHID, DHID, DHID };
    a.seg[2] = { h_lo[r], whh_hi, DHID, DHID, DHID };
    a.seg[3] = { x_b + (size_t)t * DIN, whx_b, SEQ_LEN * DIN, DIN, DIN };
    a.n_seg = 4; a.n_iters = (3 * DHID + DIN) / 64;
    a.bias = bh; a.out_hi = h_hi[w]; a.out_lo = h_lo[w]; a.out_f32 = nullptr;
    a.ldo = DHID;
    k_gemm<<<dim3(DHID / 64, B_SZ / 64), blk, 0, stream>>>(a);
  }
  // readout: p = h_T @ Wph^T + b_p   (h_T = hi + lo, t=127 wrote pair 1)
  {
    Args a = {};
    a.seg[0] = { h_hi[1], wph_b, DHID, DHID, DHID };
    a.seg[1] = { h_lo[1], wph_b, DHID, DHID, DHID };
    a.n_seg = 2; a.n_iters = 2 * DHID / 64;
    a.bias = bp; a.out_hi = nullptr; a.out_lo = nullptr;
    a.out_f32 = (float*)d_out; a.ldo = NCLS;
    k_gemm<<<dim3(NCLS / 64, B_SZ / 64), blk, 0, stream>>>(a);
  }
}

// Round 2
// 4571.566 us; speedup vs baseline: 2.1022x; 2.1022x over previous
//
#include <hip/hip_runtime.h>
#include <stdint.h>

// ---------------- problem constants ----------------
#define B_SZ   256
#define SEQ_LEN 128
#define DIN    1024
#define DHID   2048
#define NCLS   1024

#define DEPTH  6   // staging pipeline depth (tiles in flight = DEPTH-1)

typedef unsigned short ushort_t;
typedef short bf16x8 __attribute__((ext_vector_type(8)));
typedef float f32x16 __attribute__((ext_vector_type(16)));

__device__ __forceinline__ ushort_t f32_to_bf16(float f) {
  uint32_t u = __builtin_bit_cast(uint32_t, f);
  u = (u + 0x7FFFu + ((u >> 16) & 1u)) >> 16;
  return (ushort_t)u;
}
__device__ __forceinline__ float bf16_to_f32(ushort_t h) {
  uint32_t u = ((uint32_t)h) << 16;
  return __builtin_bit_cast(float, u);
}

// async global->LDS, 16B per lane. LDS dest is wave-uniform base + lane*16.
__device__ __forceinline__ void llds16(const ushort_t* g, ushort_t* l) {
  __builtin_amdgcn_global_load_lds(
      (const __attribute__((address_space(1))) void*)g,
      (__attribute__((address_space(3))) void*)l, 16, 0, 0);
}

// ---------------- conversion kernels ----------------
__global__ void k_split(const float* __restrict__ s, ushort_t* __restrict__ hi,
                        ushort_t* __restrict__ lo, int n4) {
  int i = blockIdx.x * 256 + threadIdx.x;
  if (i >= n4) return;
  float4 v = ((const float4*)s)[i];
  ushort_t h0 = f32_to_bf16(v.x), h1 = f32_to_bf16(v.y);
  ushort_t h2 = f32_to_bf16(v.z), h3 = f32_to_bf16(v.w);
  ushort4 hv; hv.x = h0; hv.y = h1; hv.z = h2; hv.w = h3;
  ushort4 lv;
  lv.x = f32_to_bf16(v.x - bf16_to_f32(h0));
  lv.y = f32_to_bf16(v.y - bf16_to_f32(h1));
  lv.z = f32_to_bf16(v.z - bf16_to_f32(h2));
  lv.w = f32_to_bf16(v.w - bf16_to_f32(h3));
  ((ushort4*)hi)[i] = hv;
  ((ushort4*)lo)[i] = lv;
}

__global__ void k_cvt(const float* __restrict__ s, ushort_t* __restrict__ d, int n4) {
  int i = blockIdx.x * 256 + threadIdx.x;
  if (i >= n4) return;
  float4 v = ((const float4*)s)[i];
  ushort4 hv;
  hv.x = f32_to_bf16(v.x); hv.y = f32_to_bf16(v.y);
  hv.z = f32_to_bf16(v.z); hv.w = f32_to_bf16(v.w);
  ((ushort4*)d)[i] = hv;
}

// ---------------- segmented-K GEMM ----------------
// C[M,N] = sum_seg A_seg[M,Kseg] * B_seg[N,Kseg]^T (+ bias). Block tile
// BM=32 x BN=64, BK=64, grid (N/64, M/32). 4 waves split K within the tile
// (wave w owns k%64 in [16w,16w+16)), mfma_f32_32x32x16_bf16, partials
// reduced through LDS. DEPTH-6 async staging pipeline (5 tiles in flight)
// so per-iter cost is bandwidth, not latency.
struct Seg {
  const ushort_t* A;
  const ushort_t* B;
  int a_stride;
  int b_stride;
  int k_len;
};
struct Args {
  Seg seg[4];
  int n_seg;
  int n_iters;          // total K / 64
  const float* bias;    // [N]
  ushort_t* out_hi;     // bf16 hi out (or null)
  ushort_t* out_lo;     // bf16 lo out
  float* out_f32;       // fp32 out (or null)
  int ldo;              // out leading dim
};

__global__ __launch_bounds__(256, 1) void k_gemm(Args args) {
  // DEPTH tiles x (A 4KB + B 8KB) = 72KB; reduce scratch (32KB) aliases it.
  __shared__ __align__(16) char pool[DEPTH * 12288];

  const int tid  = threadIdx.x;
  const int lane = tid & 63;
  const int wv   = tid >> 6;
  const int bm0  = blockIdx.y * 32;
  const int bn0  = blockIdx.x * 64;

  f32x16 acc[2];
#pragma unroll
  for (int b = 0; b < 2; ++b)
#pragma unroll
    for (int r = 0; r < 16; ++r) acc[b][r] = 0.0f;

  // staging: slot s (A: s=tid, 256 slots; B: s=tid,tid+256, 512 slots)
  // covers LDS bytes s*16 within the tile; fetches global chunk
  // glc = (s&7) ^ (row&7)  (xor swizzle; row = s>>3).
  const int prow0 = tid >> 3;
  const int glc0  = (tid & 7) ^ (prow0 & 7);
  const int prow1 = (tid + 256) >> 3;
  const int glc1  = (tid & 7) ^ (prow1 & 7);

  auto stage = [&](int buf, const Seg& sg, int k0) {
    const ushort_t* ga  = sg.A + (size_t)(bm0 + prow0) * sg.a_stride + (k0 + glc0 * 8);
    const ushort_t* gb0 = sg.B + (size_t)(bn0 + prow0) * sg.b_stride + (k0 + glc0 * 8);
    const ushort_t* gb1 = sg.B + (size_t)(bn0 + prow1) * sg.b_stride + (k0 + glc1 * 8);
    ushort_t* la = (ushort_t*)(pool + buf * 12288) + wv * 512;
    ushort_t* lb = (ushort_t*)(pool + buf * 12288 + 4096) + wv * 512;
    llds16(ga, la);         // A: 4KB total (1 llds16/thread)
    llds16(gb0, lb);        // B: 8KB total (2 llds16/thread)
    llds16(gb1, lb + 2048);
  };

  const int nit = args.n_iters;
  int sc = 0, kc = 0;
  // warmup: stage first DEPTH-1 tiles
  int nst = nit < (DEPTH - 1) ? nit : (DEPTH - 1);
  for (int s = 0; s < nst; ++s) {
    stage(s, args.seg[sc], kc);
    kc += 64;
    if (kc >= args.seg[sc].k_len) { kc = 0; ++sc; }
  }

  const int half = lane >> 5;
  const int l31  = lane & 31;
  const int lch  = wv * 2 + half;  // this wave's logical 16B-chunk within row

  int sb = DEPTH - 1;  // next stage buffer
  int cb = 0;          // current compute buffer

  for (int i = 0; i < nit; ++i) {
    int ahead = nit - 1 - i;
    if (ahead > DEPTH - 1) ahead = DEPTH - 1;
    if (i + DEPTH - 1 < nit) {
      stage(sb, args.seg[sc], kc);
      if (++sb == DEPTH) sb = 0;
      kc += 64;
      if (kc >= args.seg[sc].k_len) { kc = 0; ++sc; }
    }
    // wait until this iter's tile (oldest) landed: 3 loads per staged tile ahead
    switch (ahead) {
      case 5: __builtin_amdgcn_s_waitcnt(0x3FF0 | 15); break;
      case 4: __builtin_amdgcn_s_waitcnt(0x3FF0 | 12); break;
      case 3: __builtin_amdgcn_s_waitcnt(0x3FF0 | 9);  break;
      case 2: __builtin_amdgcn_s_waitcnt(0x3FF0 | 6);  break;
      case 1: __builtin_amdgcn_s_waitcnt(0x3FF0 | 3);  break;
      default: __builtin_amdgcn_s_waitcnt(0x3FF0 | 0); break;
    }
    __builtin_amdgcn_s_barrier();

    const ushort_t* tA = (const ushort_t*)(pool + cb * 12288);
    const ushort_t* tB = tA + 2048;

    bf16x8 af, bfm[2];
    {
      int row = l31;
      int pch = lch ^ (row & 7);
      af = *(const bf16x8*)&tA[row * 64 + pch * 8];
    }
#pragma unroll
    for (int ni = 0; ni < 2; ++ni) {
      int row = ni * 32 + l31;
      int pch = lch ^ (row & 7);
      bfm[ni] = *(const bf16x8*)&tB[row * 64 + pch * 8];
    }
#pragma unroll
    for (int ni = 0; ni < 2; ++ni)
      acc[ni] = __builtin_amdgcn_mfma_f32_32x32x16_bf16(af, bfm[ni], acc[ni], 0, 0, 0);

    if (++cb == DEPTH) cb = 0;
    __builtin_amdgcn_s_barrier();  // consume-done before this buf is re-staged
  }

  // ---- reduce 4 wave-partials (each 32x64 fp32) through LDS ----
  __syncthreads();
  float* red = (float*)pool + wv * 2048;
#pragma unroll
  for (int ni = 0; ni < 2; ++ni)
#pragma unroll
    for (int r = 0; r < 16; ++r) {
      int row = (r & 3) + 8 * (r >> 2) + 4 * half;
      int col = ni * 32 + l31;
      red[row * 64 + col] = acc[ni][r];
    }
  __syncthreads();

  const float* r0 = (const float*)pool;
  const float* r1 = r0 + 2048;
  const float* r2 = r0 + 4096;
  const float* r3 = r0 + 6144;
#pragma unroll
  for (int j = 0; j < 8; ++j) {
    int e = j * 256 + tid;
    int row = e >> 6, col = e & 63;
    float v = r0[e] + r1[e] + r2[e] + r3[e] + args.bias[bn0 + col];
    size_t o = (size_t)(bm0 + row) * args.ldo + (bn0 + col);
    if (args.out_f32) {
      args.out_f32[o] = v;
    } else {
      ushort_t h = f32_to_bf16(v);
      args.out_hi[o] = h;
      args.out_lo[o] = f32_to_bf16(v - bf16_to_f32(h));
    }
  }
}

// ---------------- launch ----------------
extern "C" void kernel_launch(void* const* d_in, const int* in_sizes, int n_in,
                              void* d_out, int out_size, void* d_ws, size_t ws_size,
                              hipStream_t stream) {
  const float* x   = (const float*)d_in[0];
  const float* Whx = (const float*)d_in[1];
  const float* Whh = (const float*)d_in[2];
  const float* Wph = (const float*)d_in[3];
  const float* bh  = (const float*)d_in[4];
  const float* bp  = (const float*)d_in[5];

  char* p = (char*)d_ws;
  ushort_t* whh_hi = (ushort_t*)p; p += (size_t)DHID * DHID * 2;
  ushort_t* whh_lo = (ushort_t*)p; p += (size_t)DHID * DHID * 2;
  ushort_t* whx_b  = (ushort_t*)p; p += (size_t)DHID * DIN * 2;
  ushort_t* wph_b  = (ushort_t*)p; p += (size_t)NCLS * DHID * 2;
  ushort_t* x_b    = (ushort_t*)p; p += (size_t)B_SZ * SEQ_LEN * DIN * 2;
  ushort_t* h_hi[2]; ushort_t* h_lo[2];
  h_hi[0] = (ushort_t*)p; p += (size_t)B_SZ * DHID * 2;
  h_lo[0] = (ushort_t*)p; p += (size_t)B_SZ * DHID * 2;
  h_hi[1] = (ushort_t*)p; p += (size_t)B_SZ * DHID * 2;
  h_lo[1] = (ushort_t*)p; p += (size_t)B_SZ * DHID * 2;

  // weight / input conversions (inputs re-poisoned every call, so redo each launch)
  {
    int n4 = DHID * DHID / 4;
    k_split<<<(n4 + 255) / 256, 256, 0, stream>>>(Whh, whh_hi, whh_lo, n4);
  }
  {
    int n4 = DHID * DIN / 4;
    k_cvt<<<(n4 + 255) / 256, 256, 0, stream>>>(Whx, whx_b, n4);
  }
  {
    int n4 = NCLS * DHID / 4;
    k_cvt<<<(n4 + 255) / 256, 256, 0, stream>>>(Wph, wph_b, n4);
  }
  {
    int n4 = B_SZ * SEQ_LEN * DIN / 4;
    k_cvt<<<(n4 + 255) / 256, 256, 0, stream>>>(x, x_b, n4);
  }

  dim3 blk(256);
  // t = 0: h = x_0 @ Whx^T + b_h
  {
    Args a = {};
    a.seg[0] = { x_b, whx_b, SEQ_LEN * DIN, DIN, DIN };
    a.n_seg = 1; a.n_iters = DIN / 64;
    a.bias = bh; a.out_hi = h_hi[0]; a.out_lo = h_lo[0]; a.out_f32 = nullptr;
    a.ldo = DHID;
    k_gemm<<<dim3(DHID / 64, B_SZ / 32), blk, 0, stream>>>(a);
  }
  // t = 1..127: h = h_prev @ Whh^T (3-product hi/lo) + x_t @ Whx^T + b_h
  for (int t = 1; t < SEQ_LEN; ++t) {
    int w = t & 1, r = w ^ 1;
    Args a = {};
    a.seg[0] = { h_hi[r], whh_hi, DHID, DHID, DHID };
    a.seg[1] = { h_hi[r], whh_lo, DHID, DHID, DHID };
    a.seg[2] = { h_lo[r], whh_hi, DHID, DHID, DHID };
    a.seg[3] = { x_b + (size_t)t * DIN, whx_b, SEQ_LEN * DIN, DIN, DIN };
    a.n_seg = 4; a.n_iters = (3 * DHID + DIN) / 64;
    a.bias = bh; a.out_hi = h_hi[w]; a.out_lo = h_lo[w]; a.out_f32 = nullptr;
    a.ldo = DHID;
    k_gemm<<<dim3(DHID / 64, B_SZ / 32), blk, 0, stream>>>(a);
  }
  // readout: p = h_T @ Wph^T + b_p   (h_T = hi + lo, t=127 wrote pair 1)
  {
    Args a = {};
    a.seg[0] = { h_hi[1], wph_b, DHID, DHID, DHID };
    a.seg[1] = { h_lo[1], wph_b, DHID, DHID, DHID };
    a.n_seg = 2; a.n_iters = 2 * DHID / 64;
    a.bias = bp; a.out_hi = nullptr; a.out_lo = nullptr;
    a.out_f32 = (float*)d_out; a.ldo = NCLS;
    k_gemm<<<dim3(NCLS / 64, B_SZ / 32), blk, 0, stream>>>(a);
  }
}